// Round 9
// baseline (336.063 us; speedup 1.0000x reference)
//
#include <hip/hip_runtime.h>
#include <hip/hip_bf16.h>
#include <math.h>

typedef unsigned short u16;
typedef float f32x4 __attribute__((ext_vector_type(4)));
typedef __bf16 bf16x8 __attribute__((ext_vector_type(8)));

__device__ __forceinline__ float bf2f(u16 u) {
    union { float f; unsigned int i; } v; v.i = ((unsigned int)u) << 16; return v.f;
}
__device__ __forceinline__ u16 f2bf(float f) {
    union { float f; unsigned int i; } v; v.f = f;
    unsigned int x = v.i;
    return (u16)((x + 0x7FFFu + ((x >> 16) & 1u)) >> 16);
}
__device__ __forceinline__ unsigned int cvt_pk_bf16(float lo, float hi) {
    unsigned int r;
    asm("v_cvt_pk_bf16_f32 %0, %1, %2" : "=v"(r) : "v"(lo), "v"(hi));
    return r;
}

// ---------------- K0: one-time weight conversion + fragment reordering ----------------
__global__ __launch_bounds__(256) void k_prep(const float* __restrict__ wq, const float* __restrict__ wkv,
                                              const float* __restrict__ w1, const float* __restrict__ w2,
                                              u16* __restrict__ wqkvb, u16* __restrict__ w1p, u16* __restrict__ w2p) {
    const int bid = blockIdx.x, t = threadIdx.x;
    if (bid < 192) {
        int e = (bid * 256 + t) * 4;
        const float* src = (e < 65536) ? (wq + e) : (wkv + (e - 65536));
        float sc = (e < 65536) ? 0.17677669529663687f : 1.f;  // fold attn scale into Q weights
        float4 v = *(const float4*)src;
        ushort4 o;
        o.x = f2bf(v.x * sc); o.y = f2bf(v.y * sc); o.z = f2bf(v.z * sc); o.w = f2bf(v.w * sc);
        *(ushort4*)(wqkvb + e) = o;
    } else if (bid < 320) {
        int tid = (bid - 192) * 256 + t;
        int kc = tid >> 11, rem = tid & 2047;
        int wave = rem >> 9, rem2 = rem & 511;
        int ks = rem2 >> 6, lane = rem2 & 63;
        int ln = lane & 15, quad = lane >> 4;
        const float* src = w1 + (size_t)(kc * 64 + wave * 16 + ln) * 256 + ks * 32 + quad * 8;
        float4 v0 = *(const float4*)src;
        float4 v1 = *(const float4*)(src + 4);
        alignas(16) u16 tmp[8];
        tmp[0] = f2bf(v0.x); tmp[1] = f2bf(v0.y); tmp[2] = f2bf(v0.z); tmp[3] = f2bf(v0.w);
        tmp[4] = f2bf(v1.x); tmp[5] = f2bf(v1.y); tmp[6] = f2bf(v1.z); tmp[7] = f2bf(v1.w);
        *(int4*)(w1p + (size_t)tid * 8) = *(int4*)tmp;
    } else {
        int tid = (bid - 320) * 256 + t;
        int kc = tid >> 11, rem = tid & 2047;
        int wave = rem >> 9, rem2 = rem & 511;
        int ks2 = rem2 >> 8, rem3 = rem2 & 255;
        int nt = rem3 >> 6, lane = rem3 & 63;
        int ln = lane & 15, quad = lane >> 4;
        const float* src = w2 + (size_t)(wave * 64 + nt * 16 + ln) * 1024 + kc * 64 + ks2 * 32 + quad * 8;
        float4 v0 = *(const float4*)src;
        float4 v1 = *(const float4*)(src + 4);
        alignas(16) u16 tmp[8];
        tmp[0] = f2bf(v0.x); tmp[1] = f2bf(v0.y); tmp[2] = f2bf(v0.z); tmp[3] = f2bf(v0.w);
        tmp[4] = f2bf(v1.x); tmp[5] = f2bf(v1.y); tmp[6] = f2bf(v1.z); tmp[7] = f2bf(v1.w);
        *(int4*)(w2p + (size_t)tid * 8) = *(int4*)tmp;
    }
}

// ---------------- K1: NCHW f32 -> NHWC bf16 transpose ----------------
__global__ __launch_bounds__(256) void k_transpose(const float* __restrict__ x, u16* __restrict__ xh) {
    __shared__ __align__(16) u16 tile[64][72];
    const int t = threadIdx.x;
    const int hw0 = blockIdx.x * 64;
    const int c0  = blockIdx.y * 64;
    const int b   = blockIdx.z;
    const int cl = t >> 2, wl = (t & 3) * 16;
    {
        int c = c0 + cl;
        const float* src = x + (size_t)(b * 256 + c) * 3136 + hw0 + wl;
        for (int q = 0; q < 4; q++) {
            float4 v = *(const float4*)(src + q * 4);
            uint2 pr;
            pr.x = cvt_pk_bf16(v.x, v.y);
            pr.y = cvt_pk_bf16(v.z, v.w);
            *(uint2*)&tile[cl][wl + q * 4] = pr;
        }
    }
    __syncthreads();
    const int hl = t >> 3, cl2 = (t & 7) * 8;
    for (int i = 0; i < 2; i++) {
        int hw = hl + i * 32;
        alignas(16) u16 tmp[8];
        for (int j = 0; j < 8; j++) tmp[j] = tile[cl2 + j][hw];
        u16* dst = xh + (size_t)(b * 3136 + hw0 + hw) * 256 + c0 + cl2;
        *(int4*)dst = *(int4*)tmp;
    }
}

// ---------------- K_ln: LayerNorm (LN1 only), bf16 in -> bf16 out ----------------
__global__ __launch_bounds__(256) void k_ln(const u16* __restrict__ in, u16* __restrict__ out,
                                            const float* __restrict__ g, const float* __restrict__ bta) {
    const int wave = threadIdx.x >> 6, lane = threadIdx.x & 63;
    const int p = blockIdx.x * 4 + wave;
    ushort4 v = *(const ushort4*)(in + (size_t)p * 256 + lane * 4);
    float f0 = bf2f(v.x), f1 = bf2f(v.y), f2 = bf2f(v.z), f3 = bf2f(v.w);
    float s = f0 + f1 + f2 + f3;
    float sq = f0 * f0 + f1 * f1 + f2 * f2 + f3 * f3;
    for (int o = 32; o >= 1; o >>= 1) { s += __shfl_xor(s, o, 64); sq += __shfl_xor(sq, o, 64); }
    float m = s * (1.f / 256.f);
    float var = sq * (1.f / 256.f) - m * m;
    float inv = rsqrtf(var + 1e-5f);
    float4 gv = *(const float4*)(g + lane * 4);
    float4 bv = *(const float4*)(bta + lane * 4);
    uint2 o2;
    o2.x = cvt_pk_bf16((f0 - m) * inv * gv.x + bv.x, (f1 - m) * inv * gv.y + bv.y);
    o2.y = cvt_pk_bf16((f2 - m) * inv * gv.z + bv.z, (f3 - m) * inv * gv.w + bv.w);
    *(uint2*)(out + (size_t)p * 256 + lane * 4) = o2;
}

// ---------------- K_qkv: qkv = xn @ wqkvb^T + [bq;bkv]  (pure-copy staging) ----------------
__global__ __launch_bounds__(256) void k_qkv(
    const u16* __restrict__ xn, const u16* __restrict__ Bw,
    const float* __restrict__ bq, const float* __restrict__ bkv,
    u16* __restrict__ out) {
    __shared__ __align__(16) u16 smem[17408];
    u16* As = smem;          // 128*32
    u16* Bs = smem + 4096;   // 128*32

    const int g = blockIdx.x;
    const int xcd = g & 7, idx = g >> 3;
    const int bm = xcd * 49 + idx / 6, bn = idx % 6;

    const int t = threadIdx.x;
    const int wave = t >> 6, lane = t & 63;
    const int wm = (wave >> 1) * 64, wn = (wave & 1) * 64;
    const int ln = lane & 15, quad = lane >> 4;

    f32x4 vzero = {0.f, 0.f, 0.f, 0.f};
    f32x4 acc[4][4];
    for (int i = 0; i < 4; i++) for (int j = 0; j < 4; j++) acc[i][j] = vzero;

    const int srow = t >> 2;
    const int scol = (t & 3) * 8;

    for (int k0 = 0; k0 < 256; k0 += 32) {
        for (int i = 0; i < 2; i++) {
            int r = srow + i * 64;
            *(int4*)&As[r * 32 + scol] = *(const int4*)(xn + (size_t)(bm * 128 + r) * 256 + k0 + scol);
            *(int4*)&Bs[r * 32 + scol] = *(const int4*)(Bw + (size_t)(bn * 128 + r) * 256 + k0 + scol);
        }
        __syncthreads();
        bf16x8 af[4], bfr[4];
        for (int mt = 0; mt < 4; mt++) af[mt] = *(const bf16x8*)&As[(wm + mt * 16 + ln) * 32 + quad * 8];
        for (int nt = 0; nt < 4; nt++) bfr[nt] = *(const bf16x8*)&Bs[(wn + nt * 16 + ln) * 32 + quad * 8];
        for (int mt = 0; mt < 4; mt++)
            for (int nt = 0; nt < 4; nt++)   // swapped: lane owns row (m), 4 consecutive cols
                acc[mt][nt] = __builtin_amdgcn_mfma_f32_16x16x32_bf16(bfr[nt], af[mt], acc[mt][nt], 0, 0, 0);
        __syncthreads();
    }

    u16* Cs = smem;  // [128][136]
    for (int nt = 0; nt < 4; nt++) {
        int gn0 = bn * 128 + wn + nt * 16 + quad * 4;
        f32x4 bv;
        if (gn0 < 256) {
            f32x4 tq = *(const f32x4*)(bq + gn0);
            bv = tq * 0.17677669529663687f;   // pre-scale Q bias
        } else {
            bv = *(const f32x4*)(bkv + gn0 - 256);
        }
        for (int mt = 0; mt < 4; mt++) {
            uint2 pk2;
            pk2.x = cvt_pk_bf16(acc[mt][nt][0] + bv[0], acc[mt][nt][1] + bv[1]);
            pk2.y = cvt_pk_bf16(acc[mt][nt][2] + bv[2], acc[mt][nt][3] + bv[3]);
            *(uint2*)&Cs[(wm + mt * 16 + ln) * 136 + wn + nt * 16 + quad * 4] = pk2;
        }
    }
    __syncthreads();
    const int row = t >> 4, col = (t & 15) * 8;
    for (int pass = 0; pass < 8; pass++) {
        int rr = pass * 16 + row;
        int4 v = *(int4*)&Cs[rr * 136 + col];
        *(int4*)(out + (size_t)(bm * 128 + rr) * 768 + bn * 128 + col) = v;
    }
}

// ---------------- K_mlp: out = x2 + g2*(gelu(ln2(x2)@w1^T+b1)@w2^T+b2), NCHW f32 ----------------
// v9 = v8 structure (single-buffered Hs, 51.2 KB LDS, unconstrained launch_bounds,
//      batched w1f/w2f prefetch) + LN2 normalize fused into A-staging using
//      PRECOMPUTED per-row stats (written by k_attn's epilogue). Unlike v7's
//      full-LN fusion, there is no raw-row register buffering and no cross-lane
//      reduce: stats are 4 float4 loads + ~15 VALU per row, normalize ~4 VALU/elem,
//      all one-time. Deletes the second k_ln dispatch + its 103 MB round trip.
//      VGPR may rise above 128: harmless (LDS caps at 3 blocks/CU = 3 waves/SIMD,
//      which only needs VGPR <= 170).
__global__ __launch_bounds__(256) void k_mlp(
    const u16* __restrict__ x2,
    const u16* __restrict__ w1p, const float* __restrict__ b1,
    const u16* __restrict__ w2p, const float* __restrict__ b2,
    const float* __restrict__ g2v,
    const float* __restrict__ ln2g, const float* __restrict__ ln2b,
    const float* __restrict__ ln2s, float* __restrict__ outT) {
    __shared__ __align__(16) u16 smem[16896 + 8704];  // As 64x264, Hs 64x136 (single)
    u16* As = smem;
    u16* Hs = smem + 16896;

    const int g = blockIdx.x;
    const int bm = (g & 7) * 98 + (g >> 3);

    const int t = threadIdx.x;
    const int wave = t >> 6, lane = t & 63;
    const int ln = lane & 15, quad = lane >> 4;
    const int wn64 = wave * 64;
    const int wq4 = wave * 2;   // w1 group base for this wave

    f32x4 vzero = {0.f, 0.f, 0.f, 0.f};
    f32x4 acc[4][4];  // [mt][nt]: n = wn64+nt*16+ln, m = mt*16+quad*4+r
    for (int i = 0; i < 4; i++) for (int j = 0; j < 4; j++) acc[i][j] = vzero;

    // ---- stage A tile with LN2 normalize from precomputed stats ----
    {
        const int srow = t >> 2, scb = (t & 3) * 8;
        const size_t prow = (size_t)(bm * 64 + srow);
        const float4* stp = (const float4*)(ln2s + prow * 16);  // 8 heads x (sum, sumsq)
        float4 s0 = stp[0], s1 = stp[1], s2 = stp[2], s3 = stp[3];
        float S = s0.x + s0.z + s1.x + s1.z + s2.x + s2.z + s3.x + s3.z;
        float Q = s0.y + s0.w + s1.y + s1.w + s2.y + s2.w + s3.y + s3.w;
        float m = S * (1.f / 256.f);
        float var = Q * (1.f / 256.f) - m * m;
        float inv = rsqrtf(var + 1e-5f);
        const u16* src = x2 + prow * 256;
        #pragma unroll
        for (int c = 0; c < 8; c++) {
            int col = scb + c * 32;
            int4 raw = *(const int4*)(src + col);
            float4 g0 = *(const float4*)(ln2g + col);
            float4 g1 = *(const float4*)(ln2g + col + 4);
            float4 b0 = *(const float4*)(ln2b + col);
            float4 b1v = *(const float4*)(ln2b + col + 4);
            const unsigned int* u = (const unsigned int*)&raw;
            float f[8];
            #pragma unroll
            for (int k = 0; k < 4; k++) {
                union { unsigned int i; float f; } lo, hi;
                lo.i = u[k] << 16; hi.i = u[k] & 0xFFFF0000u;
                f[2 * k] = lo.f; f[2 * k + 1] = hi.f;
            }
            uint4 o;
            o.x = cvt_pk_bf16((f[0] - m) * inv * g0.x + b0.x, (f[1] - m) * inv * g0.y + b0.y);
            o.y = cvt_pk_bf16((f[2] - m) * inv * g0.z + b0.z, (f[3] - m) * inv * g0.w + b0.w);
            o.z = cvt_pk_bf16((f[4] - m) * inv * g1.x + b1v.x, (f[5] - m) * inv * g1.y + b1v.y);
            o.w = cvt_pk_bf16((f[6] - m) * inv * g1.z + b1v.z, (f[7] - m) * inv * g1.w + b1v.w);
            *(uint4*)&As[srow * 264 + col] = o;
        }
    }
    __syncthreads();

    for (int kc = 0; kc < 8; kc++) {
        // ---- batch-prefetch all 16 w1 fragments for this chunk ----
        bf16x8 w1f[2][8];
        {
            const u16* w1b = w1p + (size_t)(kc * 8 + wq4) * 4096 + lane * 8;
            #pragma unroll
            for (int nt = 0; nt < 2; nt++)
                #pragma unroll
                for (int ks = 0; ks < 8; ks++)
                    w1f[nt][ks] = *(const bf16x8*)(w1b + nt * 4096 + ks * 512);
        }
        // ---- up: H chunk 64m x 128n; this wave computes 64m x 32n. ----
        f32x4 up[4][2];
        #pragma unroll
        for (int i = 0; i < 4; i++) { up[i][0] = vzero; up[i][1] = vzero; }
        #pragma unroll
        for (int ks = 0; ks < 8; ks++) {
            #pragma unroll
            for (int mt = 0; mt < 4; mt++) {
                bf16x8 af = *(const bf16x8*)&As[(mt * 16 + ln) * 264 + ks * 32 + quad * 8];
                // swapped operands: lane owns m = mt*16+ln; regs r are n = nt*16+quad*4+r
                up[mt][0] = __builtin_amdgcn_mfma_f32_16x16x32_bf16(w1f[0][ks], af, up[mt][0], 0, 0, 0);
                up[mt][1] = __builtin_amdgcn_mfma_f32_16x16x32_bf16(w1f[1][ks], af, up[mt][1], 0, 0, 0);
            }
        }
        // ---- batch-prefetch all 16 w2 fragments (issue before B1; used after B2) ----
        bf16x8 w2f[4][4];
        #pragma unroll
        for (int ks2 = 0; ks2 < 4; ks2++) {
            const u16* w2b = w2p + (size_t)((((kc * 2 + (ks2 >> 1)) * 4 + wave) * 2 + (ks2 & 1)) * 4) * 512 + lane * 8;
            #pragma unroll
            for (int nt = 0; nt < 4; nt++)
                w2f[ks2][nt] = *(const bf16x8*)(w2b + nt * 512);
        }
        // B1: all waves finished reading Hs in down(kc-1); slack = entire up phase
        __syncthreads();
        // ---- gelu (sigmoid form; downstream scaled by gamma2~1e-6) -> packed writes ----
        #pragma unroll
        for (int nt = 0; nt < 2; nt++) {
            float4 bv = *(const float4*)(b1 + kc * 128 + wave * 32 + nt * 16 + quad * 4);
            #pragma unroll
            for (int mt = 0; mt < 4; mt++) {
                float v0 = up[mt][nt][0] + bv.x;
                float v1 = up[mt][nt][1] + bv.y;
                float v2 = up[mt][nt][2] + bv.z;
                float v3 = up[mt][nt][3] + bv.w;
                uint2 pk;
                pk.x = cvt_pk_bf16(v0 * (1.f / (1.f + __expf(-1.702f * v0))),
                                   v1 * (1.f / (1.f + __expf(-1.702f * v1))));
                pk.y = cvt_pk_bf16(v2 * (1.f / (1.f + __expf(-1.702f * v2))),
                                   v3 * (1.f / (1.f + __expf(-1.702f * v3))));
                *(uint2*)&Hs[(mt * 16 + ln) * 136 + wave * 32 + nt * 16 + quad * 4] = pk;
            }
        }
        // B2: Hs writes visible
        __syncthreads();
        // ---- down: acc += H(64x128) @ W2chunk^T; K=128 in 4 slices of 32. ----
        #pragma unroll
        for (int ks2 = 0; ks2 < 4; ks2++) {
            bf16x8 hf[4];
            #pragma unroll
            for (int mt = 0; mt < 4; mt++)
                hf[mt] = *(const bf16x8*)&Hs[(mt * 16 + ln) * 136 + ks2 * 32 + quad * 8];
            #pragma unroll
            for (int nt = 0; nt < 4; nt++) {
                #pragma unroll
                for (int mt = 0; mt < 4; mt++)
                    acc[mt][nt] = __builtin_amdgcn_mfma_f32_16x16x32_bf16(hf[mt], w2f[ks2][nt], acc[mt][nt], 0, 0, 0);
            }
        }
    }

    // epilogue: lane owns channel gn, 4 consecutive positions -> float4 NCHW store
    const int b = bm / 49;
    for (int nt = 0; nt < 4; nt++) {
        int gn = wn64 + nt * 16 + ln;
        float bs = b2[gn], g2 = g2v[gn];
        for (int mt = 0; mt < 4; mt++) {
            int gm0 = bm * 64 + mt * 16 + quad * 4;
            int hw0 = gm0 - b * 3136;
            f32x4 res;
            for (int r = 0; r < 4; r++)
                res[r] = bf2f(x2[(size_t)(gm0 + r) * 256 + gn]) + g2 * (acc[mt][nt][r] + bs);
            *(f32x4*)(outT + (size_t)(b * 256 + gn) * 3136 + hw0) = res;
        }
    }
}

// ---------------- K_attn: halo attention + LayerScale residual + LN2 partial stats ----------------
// v4 structure + v9 addition: per-position channel (sum, sumsq) of the bf16-ROUNDED
// x2 values this head-block writes (32 channels), reduced over the 16-lane group
// (shfl_xor 1/2/4/8) and stored as float2 per (pos, head). k_mlp combines the 8
// head partials -> exact numerics parity with the deleted k_ln2 (stats from bf16).
__global__ __launch_bounds__(256, 4) void k_attn(
    const u16* __restrict__ qkv, const float* __restrict__ bias,
    const u16* __restrict__ xh, const float* __restrict__ gamma1,
    u16* __restrict__ x2, float* __restrict__ ln2s) {
    __shared__ __align__(16) u16 Kl[208 * 40];
    __shared__ __align__(16) u16 Vt[32 * 236];

    const int t = threadIdx.x;
    const int blk = blockIdx.x, head = blockIdx.y, b = blockIdx.z;
    const int bh = blk / 7, bw = blk - bh * 7;
    const int wave = t >> 6, lane = t & 63;
    const int ln = lane & 15, quad = lane >> 4;

    // stage K (row-major) + V (transposed scatter); invalid/halo-OOB -> zeros.
    for (int cid = t; cid < 208 * 8; cid += 256) {
        int pos = cid >> 3, part = cid & 7;
        int i = pos / 14, j = pos - i * 14;
        int gh = bh * 8 - 3 + i, gw = bw * 8 - 3 + j;
        bool valid = (pos < 196) && ((unsigned)gh < 56u) && ((unsigned)gw < 56u);
        int d0 = (part & 3) * 8;
        int4 v = {0, 0, 0, 0};
        if (valid) {
            size_t p = (size_t)(b * 56 + gh) * 56 + gw;
            v = *(const int4*)(qkv + p * 768 + 256 + head * 64 + ((part & 4) ? 32 : 0) + d0);
        }
        if (!(part & 4)) {
            *(int4*)&Kl[pos * 40 + d0] = v;
        } else {
            alignas(16) u16 tmp[8];
            *(int4*)tmp = v;
            for (int jj = 0; jj < 8; jj++) Vt[(d0 + jj) * 236 + pos] = tmp[jj];
        }
    }
    __syncthreads();

    const int qrow = wave * 16 + ln;   // this lane's q row (= softmax row)
    const int qh = bh * 8 + (qrow >> 3), qw = bw * 8 + (qrow & 7);
    const size_t qp = (size_t)(b * 56 + qh) * 56 + qw;
    bf16x8 qf = *(const bf16x8*)(qkv + qp * 768 + head * 32 + quad * 8);  // pre-scaled Q

    // QK^T swapped: s[nt][r] = S[q=qrow][k=nt*16+quad*4+r], bias as C-in.
    f32x4 s[13];
    const float* bp = bias + (size_t)(head * 64 + qrow) * 196 + quad * 4;
    #pragma unroll
    for (int nt = 0; nt < 13; nt++) {
        bf16x8 kf = *(const bf16x8*)&Kl[(nt * 16 + ln) * 40 + quad * 8];
        f32x4 c;
        if (nt < 12 || quad == 0) {
            c = *(const f32x4*)(bp + nt * 16);
        } else {
            c = (f32x4){-1e30f, -1e30f, -1e30f, -1e30f};  // k >= 196 masked
        }
        s[nt] = __builtin_amdgcn_mfma_f32_16x16x32_bf16(kf, qf, c, 0, 0, 0);
    }

    // row softmax: lane-local over 52 values + cross-quad combine (xor 16, 32)
    float mx = -1e30f;
    #pragma unroll
    for (int nt = 0; nt < 13; nt++)
        #pragma unroll
        for (int r = 0; r < 4; r++) mx = fmaxf(mx, s[nt][r]);
    mx = fmaxf(mx, __shfl_xor(mx, 16, 64));
    mx = fmaxf(mx, __shfl_xor(mx, 32, 64));
    float sum = 0.f;
    #pragma unroll
    for (int nt = 0; nt < 13; nt++)
        #pragma unroll
        for (int r = 0; r < 4; r++) {
            float e = __expf(s[nt][r] - mx);
            s[nt][r] = e;
            sum += e;
        }
    sum += __shfl_xor(sum, 16, 64);
    sum += __shfl_xor(sum, 32, 64);
    float rinv = 1.f / sum;

    // pack P rows to bf16 pairs (lane-local; k = nt*16 + quad*4 + r)
    unsigned int pk[13][2];
    #pragma unroll
    for (int nt = 0; nt < 13; nt++) {
        pk[nt][0] = cvt_pk_bf16(s[nt][0], s[nt][1]);
        pk[nt][1] = cvt_pk_bf16(s[nt][2], s[nt][3]);
    }

    // PV with common permuted k-slots: slot j<4 ~ k=32kc+4*quad+j; j>=4 ~ +16.
    f32x4 vzero = {0.f, 0.f, 0.f, 0.f};
    f32x4 o_acc[2];
    o_acc[0] = vzero; o_acc[1] = vzero;
    #pragma unroll
    for (int kc = 0; kc < 7; kc++) {
        union { int4 i4; bf16x8 v; } pu;
        pu.i4.x = pk[2 * kc][0];
        pu.i4.y = pk[2 * kc][1];
        pu.i4.z = (kc < 6) ? pk[2 * kc + 1][0] : 0;
        pu.i4.w = (kc < 6) ? pk[2 * kc + 1][1] : 0;
        #pragma unroll
        for (int n2 = 0; n2 < 2; n2++) {
            union { int4 i4; bf16x8 v; } vu;
            const u16* vb = &Vt[(n2 * 16 + ln) * 236 + kc * 32 + quad * 4];
            *(int2*)&vu.i4.x = *(const int2*)vb;
            if (kc < 6) {
                *(int2*)&vu.i4.z = *(const int2*)(vb + 16);
            } else {
                vu.i4.z = 0; vu.i4.w = 0;   // k 208..223: P slots are zero; avoid unwritten LDS
            }
            o_acc[n2] = __builtin_amdgcn_mfma_f32_16x16x32_bf16(pu.v, vu.v, o_acc[n2], 0, 0, 0);
        }
    }

    // rinv lives at lane (q, *): output row q = quad*4+r needs lane q's rinv
    float rr4[4];
    #pragma unroll
    for (int r = 0; r < 4; r++) rr4[r] = __shfl(rinv, quad * 4 + r, 16);

    float sacc[4] = {0.f, 0.f, 0.f, 0.f};
    float qacc[4] = {0.f, 0.f, 0.f, 0.f};
    #pragma unroll
    for (int n2 = 0; n2 < 2; n2++) {
        int c = head * 32 + n2 * 16 + ln;
        float g1 = gamma1[c];
        #pragma unroll
        for (int r = 0; r < 4; r++) {
            int q = wave * 16 + quad * 4 + r;
            int hh = bh * 8 + (q >> 3), ww = bw * 8 + (q & 7);
            size_t p = (size_t)(b * 56 + hh) * 56 + ww;
            float a = o_acc[n2][r] * rr4[r];
            u16 u = f2bf(bf2f(xh[p * 256 + c]) + g1 * a);
            x2[p * 256 + c] = u;
            float vq = bf2f(u);         // stats from the bf16-ROUNDED value
            sacc[r] += vq;
            qacc[r] += vq * vq;
        }
    }
    // reduce over the 16-lane group (covers this head's 32 channels: n2 x ln)
    #pragma unroll
    for (int r = 0; r < 4; r++) {
        #pragma unroll
        for (int o = 1; o < 16; o <<= 1) {
            sacc[r] += __shfl_xor(sacc[r], o, 16);
            qacc[r] += __shfl_xor(qacc[r], o, 16);
        }
    }
    if (ln == 0) {
        #pragma unroll
        for (int r = 0; r < 4; r++) {
            int q = wave * 16 + quad * 4 + r;
            int hh = bh * 8 + (q >> 3), ww = bw * 8 + (q & 7);
            size_t p = (size_t)(b * 56 + hh) * 56 + ww;
            float2 st; st.x = sacc[r]; st.y = qacc[r];
            *(float2*)(ln2s + p * 16 + head * 2) = st;
        }
    }
}

extern "C" void kernel_launch(void* const* d_in, const int* in_sizes, int n_in,
                              void* d_out, int out_size, void* d_ws, size_t ws_size,
                              hipStream_t stream) {
    const float* x      = (const float*)d_in[0];
    const float* ln1_g  = (const float*)d_in[1];
    const float* ln1_b  = (const float*)d_in[2];
    const float* wq     = (const float*)d_in[3];
    const float* bq     = (const float*)d_in[4];
    const float* wkv    = (const float*)d_in[5];
    const float* bkv    = (const float*)d_in[6];
    const float* bias   = (const float*)d_in[7];
    const float* gamma1 = (const float*)d_in[8];
    const float* ln2_g  = (const float*)d_in[9];
    const float* ln2_b  = (const float*)d_in[10];
    const float* w1     = (const float*)d_in[11];
    const float* b1     = (const float*)d_in[12];
    const float* w2     = (const float*)d_in[13];
    const float* b2     = (const float*)d_in[14];
    const float* gamma2 = (const float*)d_in[15];

    char* ws = (char*)d_ws;
    u16*   qkv   = (u16*)ws;                      // 77,070,336 B
    u16*   xh    = (u16*)(ws + 77070336);         // 25,690,112 B
    u16*   x2    = (u16*)(ws + 102760448);        // 25,690,112 B  (also reused as xn1)
    u16*   wqkvb = (u16*)(ws + 128450560);        // 393,216 B
    u16*   w1p   = (u16*)(ws + 128843776);        // 524,288 B
    u16*   w2p   = (u16*)(ws + 129368064);        // 524,288 B
    float* ln2s  = (float*)(ws + 129892352);      // 3,211,264 B (50176 pos x 8 heads x 2 f32)
    u16*   xn1   = x2;   // LN1 output; dead before k_attn writes x2

    k_prep<<<dim3(448), 256, 0, stream>>>(wq, wkv, w1, w2, wqkvb, w1p, w2p);
    k_transpose<<<dim3(49, 4, 16), 256, 0, stream>>>(x, xh);
    k_ln<<<dim3(12544), 256, 0, stream>>>(xh, xn1, ln1_g, ln1_b);
    k_qkv<<<dim3(2352), 256, 0, stream>>>(xn1, wqkvb, bq, bkv, qkv);
    k_attn<<<dim3(49, 8, 16), 256, 0, stream>>>(qkv, bias, xh, gamma1, x2, ln2s);
    k_mlp<<<dim3(784), 256, 0, stream>>>(x2, w1p, b1, w2p, b2, gamma2, ln2_g, ln2_b, ln2s, (float*)d_out);
}

// Round 10
// 334.852 us; speedup vs baseline: 1.0036x; 1.0036x over previous
//
#include <hip/hip_runtime.h>
#include <hip/hip_bf16.h>
#include <math.h>

typedef unsigned short u16;
typedef float f32x4 __attribute__((ext_vector_type(4)));
typedef __bf16 bf16x8 __attribute__((ext_vector_type(8)));

__device__ __forceinline__ float bf2f(u16 u) {
    union { float f; unsigned int i; } v; v.i = ((unsigned int)u) << 16; return v.f;
}
__device__ __forceinline__ u16 f2bf(float f) {
    union { float f; unsigned int i; } v; v.f = f;
    unsigned int x = v.i;
    return (u16)((x + 0x7FFFu + ((x >> 16) & 1u)) >> 16);
}
__device__ __forceinline__ unsigned int cvt_pk_bf16(float lo, float hi) {
    unsigned int r;
    asm("v_cvt_pk_bf16_f32 %0, %1, %2" : "=v"(r) : "v"(lo), "v"(hi));
    return r;
}

// ---------------- K0: one-time weight conversion + fragment reordering ----------------
__global__ __launch_bounds__(256) void k_prep(const float* __restrict__ wq, const float* __restrict__ wkv,
                                              const float* __restrict__ w1, const float* __restrict__ w2,
                                              u16* __restrict__ wqkvb, u16* __restrict__ w1p, u16* __restrict__ w2p) {
    const int bid = blockIdx.x, t = threadIdx.x;
    if (bid < 192) {
        int e = (bid * 256 + t) * 4;
        const float* src = (e < 65536) ? (wq + e) : (wkv + (e - 65536));
        float sc = (e < 65536) ? 0.17677669529663687f : 1.f;  // fold attn scale into Q weights
        float4 v = *(const float4*)src;
        ushort4 o;
        o.x = f2bf(v.x * sc); o.y = f2bf(v.y * sc); o.z = f2bf(v.z * sc); o.w = f2bf(v.w * sc);
        *(ushort4*)(wqkvb + e) = o;
    } else if (bid < 320) {
        int tid = (bid - 192) * 256 + t;
        int kc = tid >> 11, rem = tid & 2047;
        int wave = rem >> 9, rem2 = rem & 511;
        int ks = rem2 >> 6, lane = rem2 & 63;
        int ln = lane & 15, quad = lane >> 4;
        const float* src = w1 + (size_t)(kc * 64 + wave * 16 + ln) * 256 + ks * 32 + quad * 8;
        float4 v0 = *(const float4*)src;
        float4 v1 = *(const float4*)(src + 4);
        alignas(16) u16 tmp[8];
        tmp[0] = f2bf(v0.x); tmp[1] = f2bf(v0.y); tmp[2] = f2bf(v0.z); tmp[3] = f2bf(v0.w);
        tmp[4] = f2bf(v1.x); tmp[5] = f2bf(v1.y); tmp[6] = f2bf(v1.z); tmp[7] = f2bf(v1.w);
        *(int4*)(w1p + (size_t)tid * 8) = *(int4*)tmp;
    } else {
        int tid = (bid - 320) * 256 + t;
        int kc = tid >> 11, rem = tid & 2047;
        int wave = rem >> 9, rem2 = rem & 511;
        int ks2 = rem2 >> 8, rem3 = rem2 & 255;
        int nt = rem3 >> 6, lane = rem3 & 63;
        int ln = lane & 15, quad = lane >> 4;
        const float* src = w2 + (size_t)(wave * 64 + nt * 16 + ln) * 1024 + kc * 64 + ks2 * 32 + quad * 8;
        float4 v0 = *(const float4*)src;
        float4 v1 = *(const float4*)(src + 4);
        alignas(16) u16 tmp[8];
        tmp[0] = f2bf(v0.x); tmp[1] = f2bf(v0.y); tmp[2] = f2bf(v0.z); tmp[3] = f2bf(v0.w);
        tmp[4] = f2bf(v1.x); tmp[5] = f2bf(v1.y); tmp[6] = f2bf(v1.z); tmp[7] = f2bf(v1.w);
        *(int4*)(w2p + (size_t)tid * 8) = *(int4*)tmp;
    }
}

// ---------------- K1: NCHW f32 -> NHWC bf16 transpose ----------------
__global__ __launch_bounds__(256) void k_transpose(const float* __restrict__ x, u16* __restrict__ xh) {
    __shared__ __align__(16) u16 tile[64][72];
    const int t = threadIdx.x;
    const int hw0 = blockIdx.x * 64;
    const int c0  = blockIdx.y * 64;
    const int b   = blockIdx.z;
    const int cl = t >> 2, wl = (t & 3) * 16;
    {
        int c = c0 + cl;
        const float* src = x + (size_t)(b * 256 + c) * 3136 + hw0 + wl;
        for (int q = 0; q < 4; q++) {
            float4 v = *(const float4*)(src + q * 4);
            uint2 pr;
            pr.x = cvt_pk_bf16(v.x, v.y);
            pr.y = cvt_pk_bf16(v.z, v.w);
            *(uint2*)&tile[cl][wl + q * 4] = pr;
        }
    }
    __syncthreads();
    const int hl = t >> 3, cl2 = (t & 7) * 8;
    for (int i = 0; i < 2; i++) {
        int hw = hl + i * 32;
        alignas(16) u16 tmp[8];
        for (int j = 0; j < 8; j++) tmp[j] = tile[cl2 + j][hw];
        u16* dst = xh + (size_t)(b * 3136 + hw0 + hw) * 256 + c0 + cl2;
        *(int4*)dst = *(int4*)tmp;
    }
}

// ---------------- K_ln: LayerNorm (LN1 only), bf16 in -> bf16 out ----------------
__global__ __launch_bounds__(256) void k_ln(const u16* __restrict__ in, u16* __restrict__ out,
                                            const float* __restrict__ g, const float* __restrict__ bta) {
    const int wave = threadIdx.x >> 6, lane = threadIdx.x & 63;
    const int p = blockIdx.x * 4 + wave;
    ushort4 v = *(const ushort4*)(in + (size_t)p * 256 + lane * 4);
    float f0 = bf2f(v.x), f1 = bf2f(v.y), f2 = bf2f(v.z), f3 = bf2f(v.w);
    float s = f0 + f1 + f2 + f3;
    float sq = f0 * f0 + f1 * f1 + f2 * f2 + f3 * f3;
    for (int o = 32; o >= 1; o >>= 1) { s += __shfl_xor(s, o, 64); sq += __shfl_xor(sq, o, 64); }
    float m = s * (1.f / 256.f);
    float var = sq * (1.f / 256.f) - m * m;
    float inv = rsqrtf(var + 1e-5f);
    float4 gv = *(const float4*)(g + lane * 4);
    float4 bv = *(const float4*)(bta + lane * 4);
    uint2 o2;
    o2.x = cvt_pk_bf16((f0 - m) * inv * gv.x + bv.x, (f1 - m) * inv * gv.y + bv.y);
    o2.y = cvt_pk_bf16((f2 - m) * inv * gv.z + bv.z, (f3 - m) * inv * gv.w + bv.w);
    *(uint2*)(out + (size_t)p * 256 + lane * 4) = o2;
}

// ---------------- K_qkv: qkv = xn @ wqkvb^T + [bq;bkv]  (pure-copy staging) ----------------
__global__ __launch_bounds__(256) void k_qkv(
    const u16* __restrict__ xn, const u16* __restrict__ Bw,
    const float* __restrict__ bq, const float* __restrict__ bkv,
    u16* __restrict__ out) {
    __shared__ __align__(16) u16 smem[17408];
    u16* As = smem;          // 128*32
    u16* Bs = smem + 4096;   // 128*32

    const int g = blockIdx.x;
    const int xcd = g & 7, idx = g >> 3;
    const int bm = xcd * 49 + idx / 6, bn = idx % 6;

    const int t = threadIdx.x;
    const int wave = t >> 6, lane = t & 63;
    const int wm = (wave >> 1) * 64, wn = (wave & 1) * 64;
    const int ln = lane & 15, quad = lane >> 4;

    f32x4 vzero = {0.f, 0.f, 0.f, 0.f};
    f32x4 acc[4][4];
    for (int i = 0; i < 4; i++) for (int j = 0; j < 4; j++) acc[i][j] = vzero;

    const int srow = t >> 2;
    const int scol = (t & 3) * 8;

    for (int k0 = 0; k0 < 256; k0 += 32) {
        for (int i = 0; i < 2; i++) {
            int r = srow + i * 64;
            *(int4*)&As[r * 32 + scol] = *(const int4*)(xn + (size_t)(bm * 128 + r) * 256 + k0 + scol);
            *(int4*)&Bs[r * 32 + scol] = *(const int4*)(Bw + (size_t)(bn * 128 + r) * 256 + k0 + scol);
        }
        __syncthreads();
        bf16x8 af[4], bfr[4];
        for (int mt = 0; mt < 4; mt++) af[mt] = *(const bf16x8*)&As[(wm + mt * 16 + ln) * 32 + quad * 8];
        for (int nt = 0; nt < 4; nt++) bfr[nt] = *(const bf16x8*)&Bs[(wn + nt * 16 + ln) * 32 + quad * 8];
        for (int mt = 0; mt < 4; mt++)
            for (int nt = 0; nt < 4; nt++)   // swapped: lane owns row (m), 4 consecutive cols
                acc[mt][nt] = __builtin_amdgcn_mfma_f32_16x16x32_bf16(bfr[nt], af[mt], acc[mt][nt], 0, 0, 0);
        __syncthreads();
    }

    u16* Cs = smem;  // [128][136]
    for (int nt = 0; nt < 4; nt++) {
        int gn0 = bn * 128 + wn + nt * 16 + quad * 4;
        f32x4 bv;
        if (gn0 < 256) {
            f32x4 tq = *(const f32x4*)(bq + gn0);
            bv = tq * 0.17677669529663687f;   // pre-scale Q bias
        } else {
            bv = *(const f32x4*)(bkv + gn0 - 256);
        }
        for (int mt = 0; mt < 4; mt++) {
            uint2 pk2;
            pk2.x = cvt_pk_bf16(acc[mt][nt][0] + bv[0], acc[mt][nt][1] + bv[1]);
            pk2.y = cvt_pk_bf16(acc[mt][nt][2] + bv[2], acc[mt][nt][3] + bv[3]);
            *(uint2*)&Cs[(wm + mt * 16 + ln) * 136 + wn + nt * 16 + quad * 4] = pk2;
        }
    }
    __syncthreads();
    const int row = t >> 4, col = (t & 15) * 8;
    for (int pass = 0; pass < 8; pass++) {
        int rr = pass * 16 + row;
        int4 v = *(int4*)&Cs[rr * 136 + col];
        *(int4*)(out + (size_t)(bm * 128 + rr) * 768 + bn * 128 + col) = v;
    }
}

// ---------------- K_mlp: out = x2 + g2*(gelu(ln2(x2)@w1^T+b1)@w2^T+b2), NCHW f32 ----------------
// v10 = v9 with ln2s layout transposed to [head][pos] (see k_attn note).
//       Per-row stats = 8 L2-resident float2 loads, summed.
__global__ __launch_bounds__(256) void k_mlp(
    const u16* __restrict__ x2,
    const u16* __restrict__ w1p, const float* __restrict__ b1,
    const u16* __restrict__ w2p, const float* __restrict__ b2,
    const float* __restrict__ g2v,
    const float* __restrict__ ln2g, const float* __restrict__ ln2b,
    const float* __restrict__ ln2s, float* __restrict__ outT) {
    __shared__ __align__(16) u16 smem[16896 + 8704];  // As 64x264, Hs 64x136 (single)
    u16* As = smem;
    u16* Hs = smem + 16896;

    const int g = blockIdx.x;
    const int bm = (g & 7) * 98 + (g >> 3);

    const int t = threadIdx.x;
    const int wave = t >> 6, lane = t & 63;
    const int ln = lane & 15, quad = lane >> 4;
    const int wn64 = wave * 64;
    const int wq4 = wave * 2;   // w1 group base for this wave

    f32x4 vzero = {0.f, 0.f, 0.f, 0.f};
    f32x4 acc[4][4];  // [mt][nt]: n = wn64+nt*16+ln, m = mt*16+quad*4+r
    for (int i = 0; i < 4; i++) for (int j = 0; j < 4; j++) acc[i][j] = vzero;

    // ---- stage A tile with LN2 normalize from precomputed per-head stats ----
    {
        const int srow = t >> 2, scb = (t & 3) * 8;
        const size_t prow = (size_t)(bm * 64 + srow);
        float S = 0.f, Q = 0.f;
        #pragma unroll
        for (int h = 0; h < 8; h++) {
            float2 st = *(const float2*)(ln2s + (size_t)h * 100352 + prow * 2);
            S += st.x; Q += st.y;
        }
        float m = S * (1.f / 256.f);
        float var = Q * (1.f / 256.f) - m * m;
        float inv = rsqrtf(var + 1e-5f);
        const u16* src = x2 + prow * 256;
        #pragma unroll
        for (int c = 0; c < 8; c++) {
            int col = scb + c * 32;
            int4 raw = *(const int4*)(src + col);
            float4 g0 = *(const float4*)(ln2g + col);
            float4 g1 = *(const float4*)(ln2g + col + 4);
            float4 b0 = *(const float4*)(ln2b + col);
            float4 b1v = *(const float4*)(ln2b + col + 4);
            const unsigned int* u = (const unsigned int*)&raw;
            float f[8];
            #pragma unroll
            for (int k = 0; k < 4; k++) {
                union { unsigned int i; float f; } lo, hi;
                lo.i = u[k] << 16; hi.i = u[k] & 0xFFFF0000u;
                f[2 * k] = lo.f; f[2 * k + 1] = hi.f;
            }
            uint4 o;
            o.x = cvt_pk_bf16((f[0] - m) * inv * g0.x + b0.x, (f[1] - m) * inv * g0.y + b0.y);
            o.y = cvt_pk_bf16((f[2] - m) * inv * g0.z + b0.z, (f[3] - m) * inv * g0.w + b0.w);
            o.z = cvt_pk_bf16((f[4] - m) * inv * g1.x + b1v.x, (f[5] - m) * inv * g1.y + b1v.y);
            o.w = cvt_pk_bf16((f[6] - m) * inv * g1.z + b1v.z, (f[7] - m) * inv * g1.w + b1v.w);
            *(uint4*)&As[srow * 264 + col] = o;
        }
    }
    __syncthreads();

    for (int kc = 0; kc < 8; kc++) {
        // ---- batch-prefetch all 16 w1 fragments for this chunk ----
        bf16x8 w1f[2][8];
        {
            const u16* w1b = w1p + (size_t)(kc * 8 + wq4) * 4096 + lane * 8;
            #pragma unroll
            for (int nt = 0; nt < 2; nt++)
                #pragma unroll
                for (int ks = 0; ks < 8; ks++)
                    w1f[nt][ks] = *(const bf16x8*)(w1b + nt * 4096 + ks * 512);
        }
        // ---- up: H chunk 64m x 128n; this wave computes 64m x 32n. ----
        f32x4 up[4][2];
        #pragma unroll
        for (int i = 0; i < 4; i++) { up[i][0] = vzero; up[i][1] = vzero; }
        #pragma unroll
        for (int ks = 0; ks < 8; ks++) {
            #pragma unroll
            for (int mt = 0; mt < 4; mt++) {
                bf16x8 af = *(const bf16x8*)&As[(mt * 16 + ln) * 264 + ks * 32 + quad * 8];
                // swapped operands: lane owns m = mt*16+ln; regs r are n = nt*16+quad*4+r
                up[mt][0] = __builtin_amdgcn_mfma_f32_16x16x32_bf16(w1f[0][ks], af, up[mt][0], 0, 0, 0);
                up[mt][1] = __builtin_amdgcn_mfma_f32_16x16x32_bf16(w1f[1][ks], af, up[mt][1], 0, 0, 0);
            }
        }
        // ---- batch-prefetch all 16 w2 fragments (issue before B1; used after B2) ----
        bf16x8 w2f[4][4];
        #pragma unroll
        for (int ks2 = 0; ks2 < 4; ks2++) {
            const u16* w2b = w2p + (size_t)((((kc * 2 + (ks2 >> 1)) * 4 + wave) * 2 + (ks2 & 1)) * 4) * 512 + lane * 8;
            #pragma unroll
            for (int nt = 0; nt < 4; nt++)
                w2f[ks2][nt] = *(const bf16x8*)(w2b + nt * 512);
        }
        // B1: all waves finished reading Hs in down(kc-1); slack = entire up phase
        __syncthreads();
        // ---- gelu (sigmoid form; downstream scaled by gamma2~1e-6) -> packed writes ----
        #pragma unroll
        for (int nt = 0; nt < 2; nt++) {
            float4 bv = *(const float4*)(b1 + kc * 128 + wave * 32 + nt * 16 + quad * 4);
            #pragma unroll
            for (int mt = 0; mt < 4; mt++) {
                float v0 = up[mt][nt][0] + bv.x;
                float v1 = up[mt][nt][1] + bv.y;
                float v2 = up[mt][nt][2] + bv.z;
                float v3 = up[mt][nt][3] + bv.w;
                uint2 pk;
                pk.x = cvt_pk_bf16(v0 * (1.f / (1.f + __expf(-1.702f * v0))),
                                   v1 * (1.f / (1.f + __expf(-1.702f * v1))));
                pk.y = cvt_pk_bf16(v2 * (1.f / (1.f + __expf(-1.702f * v2))),
                                   v3 * (1.f / (1.f + __expf(-1.702f * v3))));
                *(uint2*)&Hs[(mt * 16 + ln) * 136 + wave * 32 + nt * 16 + quad * 4] = pk;
            }
        }
        // B2: Hs writes visible
        __syncthreads();
        // ---- down: acc += H(64x128) @ W2chunk^T; K=128 in 4 slices of 32. ----
        #pragma unroll
        for (int ks2 = 0; ks2 < 4; ks2++) {
            bf16x8 hf[4];
            #pragma unroll
            for (int mt = 0; mt < 4; mt++)
                hf[mt] = *(const bf16x8*)&Hs[(mt * 16 + ln) * 136 + ks2 * 32 + quad * 8];
            #pragma unroll
            for (int nt = 0; nt < 4; nt++) {
                #pragma unroll
                for (int mt = 0; mt < 4; mt++)
                    acc[mt][nt] = __builtin_amdgcn_mfma_f32_16x16x32_bf16(hf[mt], w2f[ks2][nt], acc[mt][nt], 0, 0, 0);
            }
        }
    }

    // epilogue: lane owns channel gn, 4 consecutive positions -> float4 NCHW store
    const int b = bm / 49;
    for (int nt = 0; nt < 4; nt++) {
        int gn = wn64 + nt * 16 + ln;
        float bs = b2[gn], g2 = g2v[gn];
        for (int mt = 0; mt < 4; mt++) {
            int gm0 = bm * 64 + mt * 16 + quad * 4;
            int hw0 = gm0 - b * 3136;
            f32x4 res;
            for (int r = 0; r < 4; r++)
                res[r] = bf2f(x2[(size_t)(gm0 + r) * 256 + gn]) + g2 * (acc[mt][nt][r] + bs);
            *(f32x4*)(outT + (size_t)(b * 256 + gn) * 3136 + hw0) = res;
        }
    }
}

// ---------------- K_attn: halo attention + LayerScale residual + LN2 partial stats ----------------
// v10: stats layout ln2s[head][pos] (was [pos][head]) — with [pos][head], the
// 8 head-blocks of a spatial tile (on up to 8 DIFFERENT XCDs) each wrote 8B of
// the same 64B line -> cross-XCD false sharing + partial-line RMW amplification
// on 3.2 MB. With [head][pos], each 64B line (8 consecutive positions, one
// head) is written entirely by ONE block (ww-runs are 8-aligned since 56=7*8).
__global__ __launch_bounds__(256, 4) void k_attn(
    const u16* __restrict__ qkv, const float* __restrict__ bias,
    const u16* __restrict__ xh, const float* __restrict__ gamma1,
    u16* __restrict__ x2, float* __restrict__ ln2s) {
    __shared__ __align__(16) u16 Kl[208 * 40];
    __shared__ __align__(16) u16 Vt[32 * 236];

    const int t = threadIdx.x;
    const int blk = blockIdx.x, head = blockIdx.y, b = blockIdx.z;
    const int bh = blk / 7, bw = blk - bh * 7;
    const int wave = t >> 6, lane = t & 63;
    const int ln = lane & 15, quad = lane >> 4;

    // stage K (row-major) + V (transposed scatter); invalid/halo-OOB -> zeros.
    for (int cid = t; cid < 208 * 8; cid += 256) {
        int pos = cid >> 3, part = cid & 7;
        int i = pos / 14, j = pos - i * 14;
        int gh = bh * 8 - 3 + i, gw = bw * 8 - 3 + j;
        bool valid = (pos < 196) && ((unsigned)gh < 56u) && ((unsigned)gw < 56u);
        int d0 = (part & 3) * 8;
        int4 v = {0, 0, 0, 0};
        if (valid) {
            size_t p = (size_t)(b * 56 + gh) * 56 + gw;
            v = *(const int4*)(qkv + p * 768 + 256 + head * 64 + ((part & 4) ? 32 : 0) + d0);
        }
        if (!(part & 4)) {
            *(int4*)&Kl[pos * 40 + d0] = v;
        } else {
            alignas(16) u16 tmp[8];
            *(int4*)tmp = v;
            for (int jj = 0; jj < 8; jj++) Vt[(d0 + jj) * 236 + pos] = tmp[jj];
        }
    }
    __syncthreads();

    const int qrow = wave * 16 + ln;   // this lane's q row (= softmax row)
    const int qh = bh * 8 + (qrow >> 3), qw = bw * 8 + (qrow & 7);
    const size_t qp = (size_t)(b * 56 + qh) * 56 + qw;
    bf16x8 qf = *(const bf16x8*)(qkv + qp * 768 + head * 32 + quad * 8);  // pre-scaled Q

    // QK^T swapped: s[nt][r] = S[q=qrow][k=nt*16+quad*4+r], bias as C-in.
    f32x4 s[13];
    const float* bp = bias + (size_t)(head * 64 + qrow) * 196 + quad * 4;
    #pragma unroll
    for (int nt = 0; nt < 13; nt++) {
        bf16x8 kf = *(const bf16x8*)&Kl[(nt * 16 + ln) * 40 + quad * 8];
        f32x4 c;
        if (nt < 12 || quad == 0) {
            c = *(const f32x4*)(bp + nt * 16);
        } else {
            c = (f32x4){-1e30f, -1e30f, -1e30f, -1e30f};  // k >= 196 masked
        }
        s[nt] = __builtin_amdgcn_mfma_f32_16x16x32_bf16(kf, qf, c, 0, 0, 0);
    }

    // row softmax: lane-local over 52 values + cross-quad combine (xor 16, 32)
    float mx = -1e30f;
    #pragma unroll
    for (int nt = 0; nt < 13; nt++)
        #pragma unroll
        for (int r = 0; r < 4; r++) mx = fmaxf(mx, s[nt][r]);
    mx = fmaxf(mx, __shfl_xor(mx, 16, 64));
    mx = fmaxf(mx, __shfl_xor(mx, 32, 64));
    float sum = 0.f;
    #pragma unroll
    for (int nt = 0; nt < 13; nt++)
        #pragma unroll
        for (int r = 0; r < 4; r++) {
            float e = __expf(s[nt][r] - mx);
            s[nt][r] = e;
            sum += e;
        }
    sum += __shfl_xor(sum, 16, 64);
    sum += __shfl_xor(sum, 32, 64);
    float rinv = 1.f / sum;

    // pack P rows to bf16 pairs (lane-local; k = nt*16 + quad*4 + r)
    unsigned int pk[13][2];
    #pragma unroll
    for (int nt = 0; nt < 13; nt++) {
        pk[nt][0] = cvt_pk_bf16(s[nt][0], s[nt][1]);
        pk[nt][1] = cvt_pk_bf16(s[nt][2], s[nt][3]);
    }

    // PV with common permuted k-slots: slot j<4 ~ k=32kc+4*quad+j; j>=4 ~ +16.
    f32x4 vzero = {0.f, 0.f, 0.f, 0.f};
    f32x4 o_acc[2];
    o_acc[0] = vzero; o_acc[1] = vzero;
    #pragma unroll
    for (int kc = 0; kc < 7; kc++) {
        union { int4 i4; bf16x8 v; } pu;
        pu.i4.x = pk[2 * kc][0];
        pu.i4.y = pk[2 * kc][1];
        pu.i4.z = (kc < 6) ? pk[2 * kc + 1][0] : 0;
        pu.i4.w = (kc < 6) ? pk[2 * kc + 1][1] : 0;
        #pragma unroll
        for (int n2 = 0; n2 < 2; n2++) {
            union { int4 i4; bf16x8 v; } vu;
            const u16* vb = &Vt[(n2 * 16 + ln) * 236 + kc * 32 + quad * 4];
            *(int2*)&vu.i4.x = *(const int2*)vb;
            if (kc < 6) {
                *(int2*)&vu.i4.z = *(const int2*)(vb + 16);
            } else {
                vu.i4.z = 0; vu.i4.w = 0;   // k 208..223: P slots are zero; avoid unwritten LDS
            }
            o_acc[n2] = __builtin_amdgcn_mfma_f32_16x16x32_bf16(pu.v, vu.v, o_acc[n2], 0, 0, 0);
        }
    }

    // rinv lives at lane (q, *): output row q = quad*4+r needs lane q's rinv
    float rr4[4];
    #pragma unroll
    for (int r = 0; r < 4; r++) rr4[r] = __shfl(rinv, quad * 4 + r, 16);

    float sacc[4] = {0.f, 0.f, 0.f, 0.f};
    float qacc[4] = {0.f, 0.f, 0.f, 0.f};
    #pragma unroll
    for (int n2 = 0; n2 < 2; n2++) {
        int c = head * 32 + n2 * 16 + ln;
        float g1 = gamma1[c];
        #pragma unroll
        for (int r = 0; r < 4; r++) {
            int q = wave * 16 + quad * 4 + r;
            int hh = bh * 8 + (q >> 3), ww = bw * 8 + (q & 7);
            size_t p = (size_t)(b * 56 + hh) * 56 + ww;
            float a = o_acc[n2][r] * rr4[r];
            u16 u = f2bf(bf2f(xh[p * 256 + c]) + g1 * a);
            x2[p * 256 + c] = u;
            float vq = bf2f(u);         // stats from the bf16-ROUNDED value
            sacc[r] += vq;
            qacc[r] += vq * vq;
        }
    }
    // reduce over the 16-lane group (covers this head's 32 channels: n2 x ln)
    #pragma unroll
    for (int r = 0; r < 4; r++) {
        #pragma unroll
        for (int o = 1; o < 16; o <<= 1) {
            sacc[r] += __shfl_xor(sacc[r], o, 16);
            qacc[r] += __shfl_xor(qacc[r], o, 16);
        }
    }
    if (ln == 0) {
        #pragma unroll
        for (int r = 0; r < 4; r++) {
            int q = wave * 16 + quad * 4 + r;
            int hh = bh * 8 + (q >> 3), ww = bw * 8 + (q & 7);
            size_t p = (size_t)(b * 56 + hh) * 56 + ww;
            float2 st; st.x = sacc[r]; st.y = qacc[r];
            *(float2*)(ln2s + (size_t)head * 100352 + p * 2) = st;   // [head][pos] layout
        }
    }
}

extern "C" void kernel_launch(void* const* d_in, const int* in_sizes, int n_in,
                              void* d_out, int out_size, void* d_ws, size_t ws_size,
                              hipStream_t stream) {
    const float* x      = (const float*)d_in[0];
    const float* ln1_g  = (const float*)d_in[1];
    const float* ln1_b  = (const float*)d_in[2];
    const float* wq     = (const float*)d_in[3];
    const float* bq     = (const float*)d_in[4];
    const float* wkv    = (const float*)d_in[5];
    const float* bkv    = (const float*)d_in[6];
    const float* bias   = (const float*)d_in[7];
    const float* gamma1 = (const float*)d_in[8];
    const float* ln2_g  = (const float*)d_in[9];
    const float* ln2_b  = (const float*)d_in[10];
    const float* w1     = (const float*)d_in[11];
    const float* b1     = (const float*)d_in[12];
    const float* w2     = (const float*)d_in[13];
    const float* b2     = (const float*)d_in[14];
    const float* gamma2 = (const float*)d_in[15];

    char* ws = (char*)d_ws;
    u16*   qkv   = (u16*)ws;                      // 77,070,336 B
    u16*   xh    = (u16*)(ws + 77070336);         // 25,690,112 B
    u16*   x2    = (u16*)(ws + 102760448);        // 25,690,112 B  (also reused as xn1)
    u16*   wqkvb = (u16*)(ws + 128450560);        // 393,216 B
    u16*   w1p   = (u16*)(ws + 128843776);        // 524,288 B
    u16*   w2p   = (u16*)(ws + 129368064);        // 524,288 B
    float* ln2s  = (float*)(ws + 129892352);      // 3,211,264 B (8 heads x 50176 pos x 2 f32)
    u16*   xn1   = x2;   // LN1 output; dead before k_attn writes x2

    k_prep<<<dim3(448), 256, 0, stream>>>(wq, wkv, w1, w2, wqkvb, w1p, w2p);
    k_transpose<<<dim3(49, 4, 16), 256, 0, stream>>>(x, xh);
    k_ln<<<dim3(12544), 256, 0, stream>>>(xh, xn1, ln1_g, ln1_b);
    k_qkv<<<dim3(2352), 256, 0, stream>>>(xn1, wqkvb, bq, bkv, qkv);
    k_attn<<<dim3(49, 8, 16), 256, 0, stream>>>(qkv, bias, xh, gamma1, x2, ln2s);
    k_mlp<<<dim3(784), 256, 0, stream>>>(x2, w1p, b1, w2p, b2, gamma2, ln2_g, ln2_b, ln2s, (float*)d_out);
}